// Round 1
// baseline (119.966 us; speedup 1.0000x reference)
//
#include <hip/hip_runtime.h>

typedef __attribute__((ext_vector_type(8))) short bf16x8;
typedef __attribute__((ext_vector_type(4))) float f32x4;

#define EPSV 1e-5f
// log2(e) / TEMP,  TEMP = 0.5
#define SCALE 2.885390081777927f

__device__ __forceinline__ ushort f32_to_bf16(float f) {
  union { float f; unsigned u; } cv; cv.f = f;
  unsigned u = cv.u;
  u += 0x7FFFu + ((u >> 16) & 1u);   // round-to-nearest-even
  return (ushort)(u >> 16);
}

// ---------------------------------------------------------------------------
// Kernel 1: per-patch label mean -> use_pos flag.  grid=512, block=256
// lab[b,pj,pk] = mean of main_label[b, pj*32:+32, pk*32:+32]
// ---------------------------------------------------------------------------
__global__ void cpl_label(const float* __restrict__ lab, int* __restrict__ flags) {
  const int p = blockIdx.x;
  const int b = p >> 6, pj = (p >> 3) & 7, pk = p & 7;
  const int t = threadIdx.x;
  const size_t base = ((size_t)b * 256 + pj * 32) * 256 + pk * 32;
  float s = 0.f;
#pragma unroll
  for (int i = 0; i < 4; ++i) {
    const int e = t * 4 + i;                 // 0..1023, r=e>>5, cc=e&31
    s += lab[base + (size_t)(e >> 5) * 256 + (e & 31)];
  }
#pragma unroll
  for (int d = 1; d < 64; d <<= 1) s += __shfl_xor(s, d, 64);
  __shared__ float ps[4];
  if ((t & 63) == 0) ps[t >> 6] = s;
  __syncthreads();
  if (t == 0)
    flags[p] = ((ps[0] + ps[1] + ps[2] + ps[3]) * (1.f / 1024.f) < 0.1f) ? 1 : 0;
}

// ---------------------------------------------------------------------------
// Kernel 2: repack banks [L=32, C=256, 8, 8] f32 -> [2048][256] bf16 (col-major
// over C, i.e. B^T layout for MFMA).  grid=64 (32 neg + 32 pos), block=256.
// ---------------------------------------------------------------------------
__global__ void cpl_bank(const float* __restrict__ neg, const float* __restrict__ pos,
                         ushort* __restrict__ bankN, ushort* __restrict__ bankP) {
  const int bid = blockIdx.x;
  const float* src = (bid < 32 ? neg : pos) + (size_t)(bid & 31) * 16384;
  ushort* dst = (bid < 32 ? bankN : bankP) + (size_t)(bid & 31) * 64 * 256;
  __shared__ ushort B[64 * 256];
  const int t = threadIdx.x;
#pragma unroll 8
  for (int it = 0; it < 64; ++it) {
    const int lin = it * 256 + t;            // [c][posi] linear, coalesced read
    const int c = lin >> 6, posi = lin & 63;
    B[(posi * 256 + c) ^ ((posi & 31) << 1)] = f32_to_bf16(src[lin]);
  }
  __syncthreads();
  unsigned* dst32 = (unsigned*)dst;
#pragma unroll 8
  for (int it = 0; it < 32; ++it) {
    const int lin = it * 256 + t;            // uint index: 128 uints per row
    const int posi = lin >> 7, c = (lin & 127) << 1;
    const int idx = (posi * 256 + c) ^ ((posi & 31) << 1);  // c even, swz bit0=0
    dst32[lin] = *(const unsigned*)&B[idx];
  }
}

// ---------------------------------------------------------------------------
// Kernel 3: main contrastive loss.  grid=512 (one patch each), block=256.
// Per block: stage A(64x256) to LDS bf16, pos-dot in f32; each wave keeps the
// full A tile in registers and streams 512 bank columns with MFMA 16x16x32 +
// per-lane streaming logsumexp (exp2 domain).
// ---------------------------------------------------------------------------
__global__ __launch_bounds__(256, 2) void cpl_main(
    const float* __restrict__ mainO, const float* __restrict__ emaO,
    const ushort* __restrict__ bankN, const ushort* __restrict__ bankP,
    const int* __restrict__ flags, float* __restrict__ blockSums)
{
  __shared__ ushort Asm[64 * 256];    // 32 KiB, XOR-swizzled
  __shared__ float posPart[4][64];
  __shared__ float posSim[64];
  __shared__ float mw[4][64];
  __shared__ float sw[4][64];

  const int p = blockIdx.x;
  const int b = p >> 6, pj = (p >> 3) & 7, pk = p & 7;
  const int t = threadIdx.x;
  const int n = t & 63;               // staging row (ph*8+pw)
  const int cg = t >> 6;              // c-group 0..3

  // ---- stage A to LDS (bf16) + pos-pair dot (f32) ----
  const size_t base = (((size_t)b * 256) * 64 + (pj * 8 + (n >> 3))) * 64 + pk * 8 + (n & 7);
  const float* mB = mainO + base;
  const float* eB = emaO + base;
  float pd = 0.f;
#pragma unroll 8
  for (int it = 0; it < 64; ++it) {
    const int c = it * 4 + cg;
    const float mv = mB[(size_t)c * 4096];
    const float ev = eB[(size_t)c * 4096];
    pd += mv * ev;
    Asm[(n * 256 + c) ^ ((n & 7) << 3)] = f32_to_bf16(mv);
  }
  posPart[cg][n] = pd;
  __syncthreads();
  if (t < 64)
    posSim[t] = (posPart[0][t] + posPart[1][t] + posPart[2][t] + posPart[3][t]) * SCALE;

  // ---- load A fragments: lane l holds A[mt*16 + (l&15)][ks*32 + (l>>4)*8 + j] ----
  const int l = t & 63, w = t >> 6;
  const int r16 = l & 15, kg = l >> 4;
  bf16x8 afrag[4][8];
#pragma unroll
  for (int mt = 0; mt < 4; ++mt) {
    const int row = mt * 16 + r16;
#pragma unroll
    for (int ks = 0; ks < 8; ++ks) {
      const int idx = (row * 256 + ks * 32 + kg * 8) ^ ((row & 7) << 3);
      afrag[mt][ks] = *(const bf16x8*)&Asm[idx];
    }
  }

  const ushort* bank = (flags[p] ? bankP : bankN);
  // wave w covers columns [w*512, (w+1)*512); lane covers col w*512 + nt*16 + r16
  const ushort* bptr0 = bank + (size_t)(w * 512 + r16) * 256 + kg * 8;

  float m_run[16], s_run[16];         // per (mt, reg): row = mt*16 + kg*4 + reg
#pragma unroll
  for (int e = 0; e < 16; ++e) { m_run[e] = -3.0e38f; s_run[e] = 0.f; }

  for (int nt = 0; nt < 32; ++nt) {
    const ushort* bp = bptr0 + (size_t)nt * 4096;
    bf16x8 bfrag[8];
#pragma unroll
    for (int ks = 0; ks < 8; ++ks) bfrag[ks] = *(const bf16x8*)(bp + ks * 32);
    f32x4 acc[4];
#pragma unroll
    for (int mt = 0; mt < 4; ++mt) acc[mt] = (f32x4){0.f, 0.f, 0.f, 0.f};
#pragma unroll
    for (int ks = 0; ks < 8; ++ks) {
#pragma unroll
      for (int mt = 0; mt < 4; ++mt)
        acc[mt] = __builtin_amdgcn_mfma_f32_16x16x32_bf16(afrag[mt][ks], bfrag[ks], acc[mt], 0, 0, 0);
    }
    // streaming logsumexp update (exp2 domain), one new value per (mt, reg)
#pragma unroll
    for (int mt = 0; mt < 4; ++mt) {
#pragma unroll
      for (int i = 0; i < 4; ++i) {
        const int e = mt * 4 + i;
        const float v = acc[mt][i] * SCALE;
        const float mo = m_run[e];
        const float nm = fmaxf(mo, v);
        s_run[e] = s_run[e] * exp2f(mo - nm) + exp2f(v - nm);
        m_run[e] = nm;
      }
    }
  }

  // ---- combine the 16 column-sets (lanes differing in low 4 bits) ----
#pragma unroll
  for (int d = 1; d < 16; d <<= 1) {
#pragma unroll
    for (int e = 0; e < 16; ++e) {
      const float m2 = __shfl_xor(m_run[e], d, 64);
      const float s2 = __shfl_xor(s_run[e], d, 64);
      const float nm = fmaxf(m_run[e], m2);
      s_run[e] = s_run[e] * exp2f(m_run[e] - nm) + s2 * exp2f(m2 - nm);
      m_run[e] = nm;
    }
  }
  if (r16 == 0) {
#pragma unroll
    for (int mt = 0; mt < 4; ++mt)
#pragma unroll
      for (int i = 0; i < 4; ++i) {
        const int row = mt * 16 + kg * 4 + i;
        mw[w][row] = m_run[mt * 4 + i];
        sw[w][row] = s_run[mt * 4 + i];
      }
  }
  __syncthreads();

  // ---- final per-row loss + block reduce (wave 0 only) ----
  if (t < 64) {
    float m = mw[0][t], s = sw[0][t];
#pragma unroll
    for (int ww = 1; ww < 4; ++ww) {
      const float m2 = mw[ww][t], s2 = sw[ww][t];
      const float nm = fmaxf(m, m2);
      s = s * exp2f(m - nm) + s2 * exp2f(m2 - nm);
      m = nm;
    }
    const float pos = posSim[t];
    const float M = fmaxf(m, pos);
    const float ep = exp2f(pos - M);
    const float denom = s * exp2f(m - M) + ep + EPSV;  // sum exp(allsim - M) + EPS
    float loss = -logf(ep / denom + EPSV);
#pragma unroll
    for (int d = 1; d < 64; d <<= 1) loss += __shfl_xor(loss, d, 64);
    if (t == 0) blockSums[p] = loss;
  }
}

// ---------------------------------------------------------------------------
// Kernel 4: mean of 512 block sums / (512*64).  grid=1, block=256.
// ---------------------------------------------------------------------------
__global__ void cpl_final(const float* __restrict__ blockSums, float* __restrict__ out) {
  const int t = threadIdx.x;
  float s = blockSums[t] + blockSums[t + 256];
#pragma unroll
  for (int d = 1; d < 64; d <<= 1) s += __shfl_xor(s, d, 64);
  __shared__ float ps[4];
  if ((t & 63) == 0) ps[t >> 6] = s;
  __syncthreads();
  if (t == 0) out[0] = (ps[0] + ps[1] + ps[2] + ps[3]) * (1.f / 32768.f);
}

extern "C" void kernel_launch(void* const* d_in, const int* in_sizes, int n_in,
                              void* d_out, int out_size, void* d_ws, size_t ws_size,
                              hipStream_t stream) {
  const float* mainO = (const float*)d_in[0];
  const float* emaO  = (const float*)d_in[1];
  const float* label = (const float*)d_in[2];
  const float* negB  = (const float*)d_in[3];
  const float* posB  = (const float*)d_in[4];
  float* out = (float*)d_out;

  char* ws = (char*)d_ws;
  float* blockSums = (float*)ws;                         // 512 * 4 B
  int*   flags     = (int*)(ws + 2048);                  // 512 * 4 B
  ushort* bankN    = (ushort*)(ws + 4096);               // 2048*256*2 B = 1 MiB
  ushort* bankP    = (ushort*)(ws + 4096 + 2048 * 256 * 2);

  hipLaunchKernelGGL(cpl_label, dim3(512), dim3(256), 0, stream, label, flags);
  hipLaunchKernelGGL(cpl_bank,  dim3(64),  dim3(256), 0, stream, negB, posB, bankN, bankP);
  hipLaunchKernelGGL(cpl_main,  dim3(512), dim3(256), 0, stream,
                     mainO, emaO, bankN, bankP, flags, blockSums);
  hipLaunchKernelGGL(cpl_final, dim3(1),   dim3(256), 0, stream, blockSums, out);
}

// Round 2
// 89.298 us; speedup vs baseline: 1.3434x; 1.3434x over previous
//
#include <hip/hip_runtime.h>

typedef __attribute__((ext_vector_type(8))) short bf16x8;
typedef __attribute__((ext_vector_type(4))) float f32x4;

#define EPSV 1e-5f
// (1/TEMP) * log2(e),  TEMP = 0.5  -> exp2-domain scale
#define SCALE 2.885390081777927f

__device__ __forceinline__ ushort f32_to_bf16(float f) {
  union { float f; unsigned u; } cv; cv.f = f;
  unsigned u = cv.u;
  u += 0x7FFFu + ((u >> 16) & 1u);   // round-to-nearest-even
  return (ushort)(u >> 16);
}

// ---------------------------------------------------------------------------
// Fused prep kernel, grid = 512 + 512 + 64 = 1088 blocks, 256 threads.
//  [0,512):   pack anchors  [B,C,H,W] f32 -> Apk[p][n][c] bf16 (coalesced via
//             LDS transpose) + pos-pair dot posDot[p*64+n] (f32)
//  [512,1024): per-patch label mean -> flags
//  [1024,1088): bank repack [L,C,8,8] f32 -> [2048][256] bf16, pre-scaled
// ---------------------------------------------------------------------------
__global__ __launch_bounds__(256) void cpl_prep(
    const float* __restrict__ mainO, const float* __restrict__ emaO,
    const float* __restrict__ label, const float* __restrict__ negB,
    const float* __restrict__ posB,
    ushort* __restrict__ Apk, float* __restrict__ posDot,
    int* __restrict__ flags, ushort* __restrict__ bankN, ushort* __restrict__ bankP)
{
  __shared__ ushort shU[64 * 256];   // 32 KiB
  __shared__ float  shF[4][64];
  const int bid = blockIdx.x;
  const int t = threadIdx.x;

  if (bid < 512) {
    // ---- anchor pack + pos dot: block = (b, y) ----
    const int b = bid >> 6, y = bid & 63;
    const int cg = t >> 4;            // c-offset 0..15
    const int x4 = t & 15;            // float4 index along W
    const float* mB = mainO + (((size_t)b * 256 + cg) * 64 + y) * 64 + x4 * 4;
    const float* eB = emaO  + (((size_t)b * 256 + cg) * 64 + y) * 64 + x4 * 4;
    float4 acc4 = make_float4(0.f, 0.f, 0.f, 0.f);
#pragma unroll
    for (int pass = 0; pass < 16; ++pass) {
      const int c = pass * 16 + cg;
      const float4 mv = *(const float4*)(mB + (size_t)pass * 16 * 4096);
      const float4 ev = *(const float4*)(eB + (size_t)pass * 16 * 4096);
      acc4.x += mv.x * ev.x; acc4.y += mv.y * ev.y;
      acc4.z += mv.z * ev.z; acc4.w += mv.w * ev.w;
      const float vals[4] = {mv.x, mv.y, mv.z, mv.w};
#pragma unroll
      for (int j = 0; j < 4; ++j) {
        const int x = x4 * 4 + j;
        shU[x * 256 + (c ^ ((x & 7) << 3))] = f32_to_bf16(vals[j]);
      }
    }
    // reduce pos partials over c-groups (cg bit0 = lane bit4, bit1 = lane bit5)
    acc4.x += __shfl_xor(acc4.x, 16, 64); acc4.y += __shfl_xor(acc4.y, 16, 64);
    acc4.z += __shfl_xor(acc4.z, 16, 64); acc4.w += __shfl_xor(acc4.w, 16, 64);
    acc4.x += __shfl_xor(acc4.x, 32, 64); acc4.y += __shfl_xor(acc4.y, 32, 64);
    acc4.z += __shfl_xor(acc4.z, 32, 64); acc4.w += __shfl_xor(acc4.w, 32, 64);
    if ((t & 63) < 16) *(float4*)&shF[t >> 6][(t & 15) * 4] = acc4;
    __syncthreads();
    // write packed anchors (coalesced b128)
#pragma unroll
    for (int it = 0; it < 8; ++it) {
      const int lin = it * 256 + t;          // 0..2047
      const int x = lin >> 5, c8 = lin & 31;
      const uint4 v = *(const uint4*)&shU[x * 256 + ((c8 * 8) ^ ((x & 7) << 3))];
      const int p = b * 64 + ((y >> 3) << 3) + (x >> 3);
      const int n = ((y & 7) << 3) + (x & 7);
      *(uint4*)&Apk[((size_t)p * 64 + n) * 256 + c8 * 8] = v;
    }
    if (t < 64) {
      const float pv = shF[0][t] + shF[1][t] + shF[2][t] + shF[3][t];
      const int p = b * 64 + ((y >> 3) << 3) + (t >> 3);
      const int n = ((y & 7) << 3) + (t & 7);
      posDot[p * 64 + n] = pv;
    }
  } else if (bid < 1024) {
    // ---- label mean -> flag ----
    const int p = bid - 512;
    const int b = p >> 6, pj = (p >> 3) & 7, pk = p & 7;
    const size_t base = ((size_t)b * 256 + pj * 32) * 256 + pk * 32;
    float s = 0.f;
#pragma unroll
    for (int i = 0; i < 4; ++i) {
      const int e = t * 4 + i;               // 0..1023, r=e>>5, cc=e&31
      s += label[base + (size_t)(e >> 5) * 256 + (e & 31)];
    }
#pragma unroll
    for (int d = 1; d < 64; d <<= 1) s += __shfl_xor(s, d, 64);
    if ((t & 63) == 0) shF[0][t >> 6] = s;
    __syncthreads();
    if (t == 0)
      flags[p] = ((shF[0][0] + shF[0][1] + shF[0][2] + shF[0][3]) * (1.f / 1024.f) < 0.1f) ? 1 : 0;
  } else {
    // ---- bank repack (pre-scaled by SCALE) ----
    const int bb = bid - 1024;
    const float* src = (bb < 32 ? negB : posB) + (size_t)(bb & 31) * 16384;
    ushort* dst = (bb < 32 ? bankN : bankP) + (size_t)(bb & 31) * 64 * 256;
#pragma unroll 8
    for (int it = 0; it < 64; ++it) {
      const int lin = it * 256 + t;          // [c][posi] linear, coalesced read
      const int c = lin >> 6, posi = lin & 63;
      shU[(posi * 256 + c) ^ ((posi & 31) << 1)] = f32_to_bf16(src[lin] * SCALE);
    }
    __syncthreads();
    unsigned* dst32 = (unsigned*)dst;
#pragma unroll 8
    for (int it = 0; it < 32; ++it) {
      const int lin = it * 256 + t;          // uint index: 128 uints per row
      const int posi = lin >> 7, c = (lin & 127) << 1;
      const int idx = (posi * 256 + c) ^ ((posi & 31) << 1);
      dst32[lin] = *(const unsigned*)&shU[idx];
    }
  }
}

// ---------------------------------------------------------------------------
// Main kernel: grid=512 (one patch each), block=256 (4 waves).
// A fragments loaded once from packed global (sector-perfect) and pinned in
// VGPRs; banks streamed from L2; logits shifted by pos via MFMA C-init so the
// inner loop per element is just exp2 + add (no max tracking).
// ---------------------------------------------------------------------------
__global__ __launch_bounds__(256, 2) void cpl_main(
    const ushort* __restrict__ Apk, const float* __restrict__ posDot,
    const ushort* __restrict__ bankN, const ushort* __restrict__ bankP,
    const int* __restrict__ flags, float* __restrict__ blockSums)
{
  __shared__ float posLds[64];
  __shared__ float swS[4][64];

  const int p = blockIdx.x;
  const int t = threadIdx.x;
  if (t < 64) posLds[t] = posDot[p * 64 + t] * SCALE;
  __syncthreads();

  const int l = t & 63, w = t >> 6;
  const int r16 = l & 15, kg = l >> 4;

  // ---- A fragments: lane l holds A[mt*16+(l&15)][ks*32+(l>>4)*8 + 0..7] ----
  const ushort* Ab = Apk + (size_t)p * 16384;
  bf16x8 afrag[4][8];
#pragma unroll
  for (int mt = 0; mt < 4; ++mt)
#pragma unroll
    for (int ks = 0; ks < 8; ++ks)
      afrag[mt][ks] = *(const bf16x8*)(Ab + (mt * 16 + r16) * 256 + ks * 32 + kg * 8);
  // pin fragments in registers (prevent rematerialization into the loop)
#pragma unroll
  for (int mt = 0; mt < 4; ++mt)
#pragma unroll
    for (int ks = 0; ks < 8; ++ks)
      asm volatile("" : "+v"(afrag[mt][ks]));

  // acc C-init = -pos2 for this lane's 16 rows (row = mt*16 + kg*4 + i)
  f32x4 negInit[4];
#pragma unroll
  for (int mt = 0; mt < 4; ++mt)
#pragma unroll
    for (int i = 0; i < 4; ++i)
      negInit[mt][i] = -posLds[mt * 16 + kg * 4 + i];

  const ushort* bank = (flags[p] ? bankP : bankN);
  // wave w covers columns [w*512,(w+1)*512); lane covers col w*512 + nt*16 + r16
  const ushort* bptr0 = bank + (size_t)(w * 512 + r16) * 256 + kg * 8;

  float s[16];
#pragma unroll
  for (int e = 0; e < 16; ++e) s[e] = 0.f;

  for (int nt = 0; nt < 32; ++nt) {
    const ushort* bp = bptr0 + (size_t)nt * 4096;
    bf16x8 bfrag[8];
#pragma unroll
    for (int ks = 0; ks < 8; ++ks) bfrag[ks] = *(const bf16x8*)(bp + ks * 32);
    f32x4 acc[4];
#pragma unroll
    for (int mt = 0; mt < 4; ++mt) acc[mt] = negInit[mt];
#pragma unroll
    for (int ks = 0; ks < 8; ++ks)
#pragma unroll
      for (int mt = 0; mt < 4; ++mt)
        acc[mt] = __builtin_amdgcn_mfma_f32_16x16x32_bf16(afrag[mt][ks], bfrag[ks], acc[mt], 0, 0, 0);
    // streaming denom: s += 2^(sim2 - pos2)   (overflow -> inf -> loss=-log(EPS), correct)
#pragma unroll
    for (int mt = 0; mt < 4; ++mt)
#pragma unroll
      for (int i = 0; i < 4; ++i)
        s[mt * 4 + i] += exp2f(acc[mt][i]);
  }

  // ---- sum the 16 column-partials (lanes differing in low 4 bits) ----
#pragma unroll
  for (int d = 1; d < 16; d <<= 1)
#pragma unroll
    for (int e = 0; e < 16; ++e) s[e] += __shfl_xor(s[e], d, 64);
  if (r16 == 0) {
#pragma unroll
    for (int mt = 0; mt < 4; ++mt)
#pragma unroll
      for (int i = 0; i < 4; ++i)
        swS[w][mt * 16 + kg * 4 + i] = s[mt * 4 + i];
  }
  __syncthreads();

  // ---- final per-row loss + block reduce (wave 0 only) ----
  if (t < 64) {
    const float S = 1.f + swS[0][t] + swS[1][t] + swS[2][t] + swS[3][t];
    float loss = -logf(1.f / S + EPSV);
#pragma unroll
    for (int d = 1; d < 64; d <<= 1) loss += __shfl_xor(loss, d, 64);
    if (t == 0) blockSums[p] = loss;
  }
}

// ---------------------------------------------------------------------------
// Final: mean of 512 block sums / (512*64).  grid=1, block=256.
// ---------------------------------------------------------------------------
__global__ void cpl_final(const float* __restrict__ blockSums, float* __restrict__ out) {
  const int t = threadIdx.x;
  float s = blockSums[t] + blockSums[t + 256];
#pragma unroll
  for (int d = 1; d < 64; d <<= 1) s += __shfl_xor(s, d, 64);
  __shared__ float ps[4];
  if ((t & 63) == 0) ps[t >> 6] = s;
  __syncthreads();
  if (t == 0) out[0] = (ps[0] + ps[1] + ps[2] + ps[3]) * (1.f / 32768.f);
}

extern "C" void kernel_launch(void* const* d_in, const int* in_sizes, int n_in,
                              void* d_out, int out_size, void* d_ws, size_t ws_size,
                              hipStream_t stream) {
  const float* mainO = (const float*)d_in[0];
  const float* emaO  = (const float*)d_in[1];
  const float* label = (const float*)d_in[2];
  const float* negB  = (const float*)d_in[3];
  const float* posB  = (const float*)d_in[4];
  float* out = (float*)d_out;

  char* ws = (char*)d_ws;
  float*  blockSums = (float*)ws;                        // 2 KiB
  int*    flags     = (int*)(ws + 2048);                 // 2 KiB
  ushort* bankN     = (ushort*)(ws + 4096);              // 1 MiB
  ushort* bankP     = (ushort*)(ws + 4096 + 1048576);    // 1 MiB
  float*  posDot    = (float*)(ws + 4096 + 2097152);     // 128 KiB
  ushort* Apk       = (ushort*)(ws + 4096 + 2097152 + 131072);  // 16.78 MiB

  hipLaunchKernelGGL(cpl_prep, dim3(1088), dim3(256), 0, stream,
                     mainO, emaO, label, negB, posB, Apk, posDot, flags, bankN, bankP);
  hipLaunchKernelGGL(cpl_main, dim3(512), dim3(256), 0, stream,
                     Apk, posDot, bankN, bankP, flags, blockSums);
  hipLaunchKernelGGL(cpl_final, dim3(1), dim3(256), 0, stream, blockSums, out);
}